// Round 10
// baseline (317.142 us; speedup 1.0000x reference)
//
#include <hip/hip_runtime.h>
#include <math.h>

// ---------------------------------------------------------------------------
// GAT x2 + linear + log_softmax on MI355X. R10.
//   - gat_agg reverted to 4 edge-groups x 16 lanes x bf16x4 (R8 structure,
//     which ran 49.4us; R9's 8x8 regressed to 59 via VGPR/shuffle overhead).
//     bf16 in + bf16 out retained.
//   - scatter path: ONE LDS-atomic pass (rank captured in registers from the
//     histogram atomicAdd; pass 2 re-reads src/dst from L2). Halves LDS
//     atomics/conflicts.
//   - bucket_csr: same rank-capture trick; write pass is atomic-free.
//   - bf16 chain / gemm_mfma2 / final_lsm unchanged from R9.
// ---------------------------------------------------------------------------

#define NEG_SLOPE 0.2f
#define NEG_BIG -3.0e38f

#define BSHIFT 9
#define BSIZE 512            // nodes per bucket
#define BCAP 12288           // edge capacity per bucket
#define EPB 4096             // edges per scatter block

typedef __bf16 bf16x8 __attribute__((ext_vector_type(8)));
typedef __bf16 bf16x4 __attribute__((ext_vector_type(4)));
typedef float f32x4 __attribute__((ext_vector_type(4)));

__device__ __forceinline__ float lrelu(float x) {
    return x >= 0.f ? x : NEG_SLOPE * x;
}

__device__ __forceinline__ int wave_incl_scan(int v, int lane) {
#pragma unroll
    for (int d = 1; d < 64; d <<= 1) {
        int t = __shfl_up(v, d, 64);
        if (lane >= d) v += t;
    }
    return v;
}

// ---------------- fused: bucket_scatter || gemm1 (K=128, fp32 A hi/lo) -----

__global__ __launch_bounds__(256) void fused_scatter_gemm(
        const int* __restrict__ src, const int* __restrict__ dst,
        int* __restrict__ bucketCount, unsigned* __restrict__ ebuf, int E, int SB,
        const float* __restrict__ X, const float* __restrict__ W,
        const float* __restrict__ a_src, const float* __restrict__ a_dst,
        __bf16* __restrict__ Hout, float* __restrict__ as_, float* __restrict__ ad_,
        int N, int nTiles) {
    constexpr int K = 128;
    __shared__ __bf16 Whi[64][K + 8];
    __shared__ __bf16 Wlo[64][K + 8];
    __shared__ int hist[256], base[256];

    if (blockIdx.x < (unsigned)SB) {
        // ---- scatter path: single LDS-atomic pass, rank in registers ----
        const int t = threadIdx.x;
        hist[t] = 0;
        __syncthreads();
        const int e0 = blockIdx.x * EPB;
        const int e1 = min(e0 + EPB, E);
        int rr[EPB / 256];
#pragma unroll
        for (int i = 0; i < EPB / 256; ++i) {
            int e = e0 + i * 256 + t;
            if (e < e1) rr[i] = atomicAdd(&hist[dst[e] >> BSHIFT], 1);
        }
        __syncthreads();
        if (hist[t] > 0) base[t] = atomicAdd(&bucketCount[t], hist[t]);
        __syncthreads();
#pragma unroll
        for (int i = 0; i < EPB / 256; ++i) {
            int e = e0 + i * 256 + t;
            if (e < e1) {
                int d = dst[e];
                int b = d >> BSHIFT;
                __builtin_nontemporal_store(
                    ((unsigned)src[e] << BSHIFT) | (unsigned)(d & (BSIZE - 1)),
                    &ebuf[(size_t)b * BCAP + base[b] + rr[i]]);
            }
        }
        return;
    }

    // ---- gemm path ----
    const int gbid = blockIdx.x - SB;
    for (int idx = threadIdx.x; idx < K * 64; idx += 256) {
        int k = idx >> 6, n = idx & 63;
        float w = W[idx];
        __bf16 hi = (__bf16)w;
        Whi[n][k] = hi;
        Wlo[n][k] = (__bf16)(w - (float)hi);
    }
    __syncthreads();

    const int lane  = threadIdx.x & 63;
    const int wave  = threadIdx.x >> 6;
    const int row16 = lane & 15;
    const int quad  = lane >> 4;

    float asv[4], adv[4];
#pragma unroll
    for (int t = 0; t < 4; ++t) {
        asv[t] = a_src[t * 16 + row16];
        adv[t] = a_dst[t * 16 + row16];
    }

    for (int tile = gbid; tile < nTiles; tile += 1024) {
        const int nbase = tile * 64;
        int gn = nbase + wave * 16 + row16;
        if (gn >= N) gn = N - 1;
        const float* __restrict__ xp = X + (size_t)gn * K + quad * 8;

        float4 xv[K / 16];
#pragma unroll
        for (int c = 0; c < K / 32; ++c) {
            xv[2 * c]     = *(const float4*)(xp + c * 32);
            xv[2 * c + 1] = *(const float4*)(xp + c * 32 + 4);
        }

        f32x4 acc[4] = {{0.f, 0.f, 0.f, 0.f}, {0.f, 0.f, 0.f, 0.f},
                        {0.f, 0.f, 0.f, 0.f}, {0.f, 0.f, 0.f, 0.f}};
#pragma unroll
        for (int kc = 0; kc < K; kc += 32) {
            float xs[8];
            *(float4*)&xs[0] = xv[kc / 16];
            *(float4*)&xs[4] = xv[kc / 16 + 1];
            bf16x8 ahi, alo;
#pragma unroll
            for (int j = 0; j < 8; ++j) {
                __bf16 hi = (__bf16)xs[j];
                ahi[j] = hi;
                alo[j] = (__bf16)(xs[j] - (float)hi);
            }
#pragma unroll
            for (int t = 0; t < 4; ++t) {
                bf16x8 bhi = *(const bf16x8*)&Whi[t * 16 + row16][kc + quad * 8];
                bf16x8 blo = *(const bf16x8*)&Wlo[t * 16 + row16][kc + quad * 8];
                acc[t] = __builtin_amdgcn_mfma_f32_16x16x32_bf16(ahi, bhi, acc[t], 0, 0, 0);
                acc[t] = __builtin_amdgcn_mfma_f32_16x16x32_bf16(ahi, blo, acc[t], 0, 0, 0);
                acc[t] = __builtin_amdgcn_mfma_f32_16x16x32_bf16(alo, bhi, acc[t], 0, 0, 0);
            }
        }

        float ps[4] = {0.f, 0.f, 0.f, 0.f};
        float pd[4] = {0.f, 0.f, 0.f, 0.f};
#pragma unroll
        for (int t = 0; t < 4; ++t) {
#pragma unroll
            for (int r = 0; r < 4; ++r) {
                int gm = nbase + wave * 16 + quad * 4 + r;
                if (gm < N) Hout[(size_t)gm * 64 + t * 16 + row16] = (__bf16)acc[t][r];
                ps[r] = fmaf(acc[t][r], asv[t], ps[r]);
                pd[r] = fmaf(acc[t][r], adv[t], pd[r]);
            }
        }
#pragma unroll
        for (int r = 0; r < 4; ++r) {
#pragma unroll
            for (int d = 1; d < 16; d <<= 1) {
                ps[r] += __shfl_xor(ps[r], d, 64);
                pd[r] += __shfl_xor(pd[r], d, 64);
            }
        }
        if (row16 == 0) {
#pragma unroll
            for (int r = 0; r < 4; ++r) {
                int gm = nbase + wave * 16 + quad * 4 + r;
                if (gm < N) { as_[gm] = ps[r]; ad_[gm] = pd[r]; }
            }
        }
    }
}

// ---------------- per-bucket CSR (rank-capture, atomic-free writes) --------

__global__ __launch_bounds__(512) void bucket_csr(const unsigned* __restrict__ ebuf,
                                                  const int* __restrict__ bucketCount,
                                                  int* __restrict__ offs,
                                                  int* __restrict__ csr, int N, int E) {
    __shared__ int hist[512], excls[512], wsum[8];
    const int b = blockIdx.x;
    const int t = threadIdx.x;
    const int lane = t & 63;
    const int w = t >> 6;

    // gbase = sum of bucketCount[0..b-1] via reduction
    int v = (t < 256 && t < b) ? bucketCount[t] : 0;
#pragma unroll
    for (int d = 32; d; d >>= 1) v += __shfl_xor(v, d, 64);
    if (lane == 0) wsum[w] = v;
    hist[t] = 0;
    __syncthreads();
    int gbase = 0;
#pragma unroll
    for (int i = 0; i < 8; ++i) gbase += wsum[i];
    const int cnt = bucketCount[b];
    if (b == 0 && t == 0) offs[N] = E;

    const unsigned* __restrict__ eb = ebuf + (size_t)b * BCAP;
    int rr[BCAP / 512];
#pragma unroll
    for (int i = 0; i < BCAP / 512; ++i) {
        int idx = i * 512 + t;
        if (idx < cnt) rr[i] = atomicAdd(&hist[eb[idx] & (BSIZE - 1)], 1);
    }
    __syncthreads();

    // 512-entry exclusive scan: wave scans + cross-wave combine
    int hv = hist[t];
    int incl = wave_incl_scan(hv, lane);
    if (lane == 63) wsum[w] = incl;
    __syncthreads();
    int prefix = 0;
    for (int i = 0; i < 8; ++i) prefix += (i < w) ? wsum[i] : 0;
    int excl = incl - hv + prefix;
    int n = b * BSIZE + t;
    if (n < N) offs[n] = gbase + excl;
    excls[t] = excl;
    __syncthreads();

#pragma unroll
    for (int i = 0; i < BCAP / 512; ++i) {
        int idx = i * 512 + t;
        if (idx < cnt) {
            unsigned rec = eb[idx];
            csr[gbase + excls[rec & (BSIZE - 1)] + rr[i]] = (int)(rec >> BSHIFT);
        }
    }
}

// ---------------- MFMA GEMM layer-2 (K=64, bf16 A, 2-term) ----------------

__global__ __launch_bounds__(256) void gemm_mfma2(const __bf16* __restrict__ X,
                                                  const float* __restrict__ W,
                                                  const float* __restrict__ a_src,
                                                  const float* __restrict__ a_dst,
                                                  __bf16* __restrict__ Hout,
                                                  float* __restrict__ as_,
                                                  float* __restrict__ ad_,
                                                  int N, int nTiles) {
    constexpr int K = 64;
    __shared__ __bf16 Whi[64][K + 8];
    __shared__ __bf16 Wlo[64][K + 8];
    for (int idx = threadIdx.x; idx < K * 64; idx += 256) {
        int k = idx >> 6, n = idx & 63;
        float w = W[idx];
        __bf16 hi = (__bf16)w;
        Whi[n][k] = hi;
        Wlo[n][k] = (__bf16)(w - (float)hi);
    }
    __syncthreads();

    const int lane  = threadIdx.x & 63;
    const int wave  = threadIdx.x >> 6;
    const int row16 = lane & 15;
    const int quad  = lane >> 4;

    float asv[4], adv[4];
#pragma unroll
    for (int t = 0; t < 4; ++t) {
        asv[t] = a_src[t * 16 + row16];
        adv[t] = a_dst[t * 16 + row16];
    }

    for (int tile = blockIdx.x; tile < nTiles; tile += gridDim.x) {
        const int nbase = tile * 64;
        int gn = nbase + wave * 16 + row16;
        if (gn >= N) gn = N - 1;
        const __bf16* __restrict__ xp = X + (size_t)gn * K + quad * 8;
        bf16x8 a0 = *(const bf16x8*)(xp);
        bf16x8 a1 = *(const bf16x8*)(xp + 32);

        f32x4 acc[4] = {{0.f, 0.f, 0.f, 0.f}, {0.f, 0.f, 0.f, 0.f},
                        {0.f, 0.f, 0.f, 0.f}, {0.f, 0.f, 0.f, 0.f}};
#pragma unroll
        for (int kc = 0; kc < K; kc += 32) {
            bf16x8 a = (kc == 0) ? a0 : a1;
#pragma unroll
            for (int t = 0; t < 4; ++t) {
                bf16x8 bhi = *(const bf16x8*)&Whi[t * 16 + row16][kc + quad * 8];
                bf16x8 blo = *(const bf16x8*)&Wlo[t * 16 + row16][kc + quad * 8];
                acc[t] = __builtin_amdgcn_mfma_f32_16x16x32_bf16(a, bhi, acc[t], 0, 0, 0);
                acc[t] = __builtin_amdgcn_mfma_f32_16x16x32_bf16(a, blo, acc[t], 0, 0, 0);
            }
        }

        float ps[4] = {0.f, 0.f, 0.f, 0.f};
        float pd[4] = {0.f, 0.f, 0.f, 0.f};
#pragma unroll
        for (int t = 0; t < 4; ++t) {
#pragma unroll
            for (int r = 0; r < 4; ++r) {
                int gm = nbase + wave * 16 + quad * 4 + r;
                if (gm < N) Hout[(size_t)gm * 64 + t * 16 + row16] = (__bf16)acc[t][r];
                ps[r] = fmaf(acc[t][r], asv[t], ps[r]);
                pd[r] = fmaf(acc[t][r], adv[t], pd[r]);
            }
        }
#pragma unroll
        for (int r = 0; r < 4; ++r) {
#pragma unroll
            for (int d = 1; d < 16; d <<= 1) {
                ps[r] += __shfl_xor(ps[r], d, 64);
                pd[r] += __shfl_xor(pd[r], d, 64);
            }
        }
        if (row16 == 0) {
#pragma unroll
            for (int r = 0; r < 4; ++r) {
                int gm = nbase + wave * 16 + quad * 4 + r;
                if (gm < N) { as_[gm] = ps[r]; ad_[gm] = pd[r]; }
            }
        }
    }
}

// ---------------- fused segment softmax + aggregation (4x16, bf16x4) -------

__global__ __launch_bounds__(256) void gat_agg(const __bf16* __restrict__ h,
                                               const float* __restrict__ as_,
                                               const float* __restrict__ ad_,
                                               const float* __restrict__ bias,
                                               const int* __restrict__ offs,
                                               const int* __restrict__ csr,
                                               __bf16* __restrict__ out,
                                               int N, int do_relu) {
    int gtid = blockIdx.x * blockDim.x + threadIdx.x;
    int n = __builtin_amdgcn_readfirstlane(gtid >> 6);
    if (n >= N) return;
    const int lane = threadIdx.x & 63;
    const int g  = lane >> 4;   // edge group 0..3
    const int fl = lane & 15;   // feature quad index

    int beg = offs[n], end = offs[n + 1];
    float adn = ad_[n];
    float p_self = __expf(lrelu(as_[n] + adn));

    float den = p_self;
    float ax, ay, az, aw;
    {
        bf16x4 t = *(const bf16x4*)(h + (size_t)n * 64 + fl * 4);
        float m0 = (g == 0) ? p_self : 0.f;
        ax = m0 * (float)t[0];
        ay = m0 * (float)t[1];
        az = m0 * (float)t[2];
        aw = m0 * (float)t[3];
    }

    for (int c0 = beg; c0 < end; c0 += 64) {
        int cnt = end - c0;
        if (cnt > 64) cnt = 64;
        int   s_l = (lane < cnt) ? csr[c0 + lane] : 0;
        float p_l = (lane < cnt) ? __expf(lrelu(as_[s_l] + adn)) : 0.f;
        float csum = p_l;
#pragma unroll
        for (int d = 32; d; d >>= 1) csum += __shfl_xor(csum, d, 64);
        den += csum;

        int rounds = (cnt + 3) >> 2;
        for (int r = 0; r < rounds; r += 4) {
            int j0 = (r + 0) * 4 + g, j1 = (r + 1) * 4 + g;
            int j2 = (r + 2) * 4 + g, j3 = (r + 3) * 4 + g;
            float w0 = __shfl(p_l, j0, 64), w1 = __shfl(p_l, j1, 64);
            float w2 = __shfl(p_l, j2, 64), w3 = __shfl(p_l, j3, 64);
            int s0 = __shfl(s_l, j0, 64), s1 = __shfl(s_l, j1, 64);
            int s2 = __shfl(s_l, j2, 64), s3 = __shfl(s_l, j3, 64);
            bf16x4 h0 = *(const bf16x4*)(h + (size_t)s0 * 64 + fl * 4);
            bf16x4 h1 = *(const bf16x4*)(h + (size_t)s1 * 64 + fl * 4);
            bf16x4 h2 = *(const bf16x4*)(h + (size_t)s2 * 64 + fl * 4);
            bf16x4 h3 = *(const bf16x4*)(h + (size_t)s3 * 64 + fl * 4);
            ax = fmaf(w0, (float)h0[0], ax); ay = fmaf(w0, (float)h0[1], ay);
            az = fmaf(w0, (float)h0[2], az); aw = fmaf(w0, (float)h0[3], aw);
            ax = fmaf(w1, (float)h1[0], ax); ay = fmaf(w1, (float)h1[1], ay);
            az = fmaf(w1, (float)h1[2], az); aw = fmaf(w1, (float)h1[3], aw);
            ax = fmaf(w2, (float)h2[0], ax); ay = fmaf(w2, (float)h2[1], ay);
            az = fmaf(w2, (float)h2[2], az); aw = fmaf(w2, (float)h2[3], aw);
            ax = fmaf(w3, (float)h3[0], ax); ay = fmaf(w3, (float)h3[1], ay);
            az = fmaf(w3, (float)h3[2], az); aw = fmaf(w3, (float)h3[3], aw);
        }
    }

#pragma unroll
    for (int d = 16; d <= 32; d <<= 1) {
        ax += __shfl_xor(ax, d, 64);
        ay += __shfl_xor(ay, d, 64);
        az += __shfl_xor(az, d, 64);
        aw += __shfl_xor(aw, d, 64);
    }
    if (g == 0) {
        float inv = 1.f / (den + 1e-16f);
        const float4 b4 = *(const float4*)(bias + fl * 4);
        bf16x4 ov;
        float o0 = fmaf(ax, inv, b4.x);
        float o1 = fmaf(ay, inv, b4.y);
        float o2 = fmaf(az, inv, b4.z);
        float o3 = fmaf(aw, inv, b4.w);
        if (do_relu) {
            o0 = fmaxf(o0, 0.f); o1 = fmaxf(o1, 0.f);
            o2 = fmaxf(o2, 0.f); o3 = fmaxf(o3, 0.f);
        }
        ov[0] = (__bf16)o0; ov[1] = (__bf16)o1;
        ov[2] = (__bf16)o2; ov[3] = (__bf16)o3;
        *(bf16x4*)(out + (size_t)n * 64 + fl * 4) = ov;
    }
}

// ---------------- final linear (bf16 A, 2-term) + log_softmax --------------

__global__ __launch_bounds__(256) void final_lsm(const __bf16* __restrict__ h,
                                                 const float* __restrict__ Wl,
                                                 const float* __restrict__ bl,
                                                 float* __restrict__ out,
                                                 int N, int nTiles) {
    __shared__ __bf16 Whi[48][72];
    __shared__ __bf16 Wlo[48][72];
    __shared__ float bls[48];
    for (int idx = threadIdx.x; idx < 48 * 64; idx += 256) {
        int c = idx >> 6, k = idx & 63;
        float w = (c < 40) ? Wl[k * 40 + c] : 0.f;
        __bf16 hi = (__bf16)w;
        Whi[c][k] = hi;
        Wlo[c][k] = (__bf16)(w - (float)hi);
    }
    if (threadIdx.x < 48) bls[threadIdx.x] = (threadIdx.x < 40) ? bl[threadIdx.x] : 0.f;
    __syncthreads();

    const int lane  = threadIdx.x & 63;
    const int wave  = threadIdx.x >> 6;
    const int col16 = lane & 15;
    const int quad  = lane >> 4;

    for (int tile = blockIdx.x; tile < nTiles; tile += gridDim.x) {
        const int nbase = tile * 64;
        int gn = nbase + wave * 16 + col16;
        if (gn >= N) gn = N - 1;
        const __bf16* __restrict__ xp = h + (size_t)gn * 64 + quad * 8;
        bf16x8 a0 = *(const bf16x8*)(xp);
        bf16x8 a1 = *(const bf16x8*)(xp + 32);

        f32x4 acc[3] = {{0.f, 0.f, 0.f, 0.f}, {0.f, 0.f, 0.f, 0.f},
                        {0.f, 0.f, 0.f, 0.f}};
#pragma unroll
        for (int kc = 0; kc < 64; kc += 32) {
            bf16x8 a = (kc == 0) ? a0 : a1;
#pragma unroll
            for (int t = 0; t < 3; ++t) {
                bf16x8 bhi = *(const bf16x8*)&Whi[t * 16 + col16][kc + quad * 8];
                bf16x8 blo = *(const bf16x8*)&Wlo[t * 16 + col16][kc + quad * 8];
                acc[t] = __builtin_amdgcn_mfma_f32_16x16x32_bf16(a, bhi, acc[t], 0, 0, 0);
                acc[t] = __builtin_amdgcn_mfma_f32_16x16x32_bf16(a, blo, acc[t], 0, 0, 0);
            }
        }

#pragma unroll
        for (int r = 0; r < 4; ++r) {
            int gm = nbase + wave * 16 + quad * 4 + r;
            float l0 = acc[0][r] + bls[col16];
            float l1 = acc[1][r] + bls[16 + col16];
            float l2 = (col16 < 8) ? (acc[2][r] + bls[32 + col16]) : NEG_BIG;
            float mx = fmaxf(fmaxf(l0, l1), l2);
#pragma unroll
            for (int d = 1; d < 16; d <<= 1) mx = fmaxf(mx, __shfl_xor(mx, d, 64));
            float s = __expf(l0 - mx) + __expf(l1 - mx) +
                      ((col16 < 8) ? __expf(l2 - mx) : 0.f);
#pragma unroll
            for (int d = 1; d < 16; d <<= 1) s += __shfl_xor(s, d, 64);
            float lse = mx + __logf(s);
            if (gm < N) {
                out[(size_t)gm * 40 + col16]      = l0 - lse;
                out[(size_t)gm * 40 + 16 + col16] = l1 - lse;
                if (col16 < 8) out[(size_t)gm * 40 + 32 + col16] = l2 - lse;
            }
        }
    }
}

// ---------------- launch ----------------

extern "C" void kernel_launch(void* const* d_in, const int* in_sizes, int n_in,
                              void* d_out, int out_size, void* d_ws, size_t ws_size,
                              hipStream_t stream) {
    const float* x      = (const float*)d_in[0];
    const int*   ei     = (const int*)d_in[1];
    const float* W1     = (const float*)d_in[2];
    const float* a_src1 = (const float*)d_in[3];
    const float* a_dst1 = (const float*)d_in[4];
    const float* b1     = (const float*)d_in[5];
    const float* W2     = (const float*)d_in[6];
    const float* a_src2 = (const float*)d_in[7];
    const float* a_dst2 = (const float*)d_in[8];
    const float* b2     = (const float*)d_in[9];
    const float* Wl     = (const float*)d_in[10];
    const float* bl     = (const float*)d_in[11];

    const int N = in_sizes[0] / 128;
    const int E = in_sizes[1] / 2;
    const int* src = ei;
    const int* dst = ei + E;
    const int nbuck = (N + BSIZE - 1) >> BSHIFT;
    const int SB = (E + EPB - 1) / EPB;

    char* p = (char*)d_ws;
    auto alloc = [&](size_t bytes) -> void* {
        void* r = (void*)p;
        p += (bytes + 255) & ~(size_t)255;
        return r;
    };
    int*      offs        = (int*)alloc((size_t)(N + 1) * 4);
    int*      bucketCount = (int*)alloc(256 * 4);
    unsigned* ebuf        = (unsigned*)alloc((size_t)nbuck * BCAP * 4);
    int*      csr         = (int*)alloc((size_t)E * 4);
    __bf16*   hbf         = (__bf16*)alloc((size_t)N * 64 * 2);  // gemm h out
    __bf16*   habg        = (__bf16*)alloc((size_t)N * 64 * 2);  // agg out
    float*    as_         = (float*)alloc((size_t)N * 4);
    float*    ad_         = (float*)alloc((size_t)N * 4);

    hipMemsetAsync(bucketCount, 0, 256 * 4, stream);

    const int nTiles = (N + 63) / 64;
    int aggBlocks = (N * 64 + 255) / 256;

    fused_scatter_gemm<<<SB + 1024, 256, 0, stream>>>(
        src, dst, bucketCount, ebuf, E, SB,
        x, W1, a_src1, a_dst1, hbf, as_, ad_, N, nTiles);
    bucket_csr<<<nbuck, 512, 0, stream>>>(ebuf, bucketCount, offs, csr, N, E);
    gat_agg<<<aggBlocks, 256, 0, stream>>>(hbf, as_, ad_, b1, offs, csr, habg, N, 1);
    gemm_mfma2<<<1024, 256, 0, stream>>>(habg, W2, a_src2, a_dst2, hbf, as_, ad_, N, nTiles);
    gat_agg<<<aggBlocks, 256, 0, stream>>>(hbf, as_, ad_, b2, offs, csr, habg, N, 0);
    final_lsm<<<nTiles, 256, 0, stream>>>(habg, Wl, bl, (float*)d_out, N, nTiles);
}

// Round 11
// 281.651 us; speedup vs baseline: 1.1260x; 1.1260x over previous
//
#include <hip/hip_runtime.h>
#include <math.h>

// ---------------------------------------------------------------------------
// GAT x2 + linear + log_softmax on MI355X. R11.
//   - R10 minus the ebuf nontemporal store (that NT store forced ~100MB of
//     HBM write-through + HBM re-reads in bucket_csr; regular stores keep
//     ebuf L2-resident). Rank-capture single-atomic-pass scatter retained.
//   - Everything else unchanged from R10 (bf16 chain, 4x16 gat_agg,
//     rank-capture bucket_csr, fused scatter||gemm1).
// ---------------------------------------------------------------------------

#define NEG_SLOPE 0.2f
#define NEG_BIG -3.0e38f

#define BSHIFT 9
#define BSIZE 512            // nodes per bucket
#define BCAP 12288           // edge capacity per bucket
#define EPB 4096             // edges per scatter block

typedef __bf16 bf16x8 __attribute__((ext_vector_type(8)));
typedef __bf16 bf16x4 __attribute__((ext_vector_type(4)));
typedef float f32x4 __attribute__((ext_vector_type(4)));

__device__ __forceinline__ float lrelu(float x) {
    return x >= 0.f ? x : NEG_SLOPE * x;
}

__device__ __forceinline__ int wave_incl_scan(int v, int lane) {
#pragma unroll
    for (int d = 1; d < 64; d <<= 1) {
        int t = __shfl_up(v, d, 64);
        if (lane >= d) v += t;
    }
    return v;
}

// ---------------- fused: bucket_scatter || gemm1 (K=128, fp32 A hi/lo) -----

__global__ __launch_bounds__(256) void fused_scatter_gemm(
        const int* __restrict__ src, const int* __restrict__ dst,
        int* __restrict__ bucketCount, unsigned* __restrict__ ebuf, int E, int SB,
        const float* __restrict__ X, const float* __restrict__ W,
        const float* __restrict__ a_src, const float* __restrict__ a_dst,
        __bf16* __restrict__ Hout, float* __restrict__ as_, float* __restrict__ ad_,
        int N, int nTiles) {
    constexpr int K = 128;
    __shared__ __bf16 Whi[64][K + 8];
    __shared__ __bf16 Wlo[64][K + 8];
    __shared__ int hist[256], base[256];

    if (blockIdx.x < (unsigned)SB) {
        // ---- scatter path: single LDS-atomic pass, rank in registers ----
        const int t = threadIdx.x;
        hist[t] = 0;
        __syncthreads();
        const int e0 = blockIdx.x * EPB;
        const int e1 = min(e0 + EPB, E);
        int rr[EPB / 256];
#pragma unroll
        for (int i = 0; i < EPB / 256; ++i) {
            int e = e0 + i * 256 + t;
            if (e < e1) rr[i] = atomicAdd(&hist[dst[e] >> BSHIFT], 1);
        }
        __syncthreads();
        if (hist[t] > 0) base[t] = atomicAdd(&bucketCount[t], hist[t]);
        __syncthreads();
#pragma unroll
        for (int i = 0; i < EPB / 256; ++i) {
            int e = e0 + i * 256 + t;
            if (e < e1) {
                int d = dst[e];
                int b = d >> BSHIFT;
                ebuf[(size_t)b * BCAP + base[b] + rr[i]] =
                    ((unsigned)src[e] << BSHIFT) | (unsigned)(d & (BSIZE - 1));
            }
        }
        return;
    }

    // ---- gemm path ----
    const int gbid = blockIdx.x - SB;
    for (int idx = threadIdx.x; idx < K * 64; idx += 256) {
        int k = idx >> 6, n = idx & 63;
        float w = W[idx];
        __bf16 hi = (__bf16)w;
        Whi[n][k] = hi;
        Wlo[n][k] = (__bf16)(w - (float)hi);
    }
    __syncthreads();

    const int lane  = threadIdx.x & 63;
    const int wave  = threadIdx.x >> 6;
    const int row16 = lane & 15;
    const int quad  = lane >> 4;

    float asv[4], adv[4];
#pragma unroll
    for (int t = 0; t < 4; ++t) {
        asv[t] = a_src[t * 16 + row16];
        adv[t] = a_dst[t * 16 + row16];
    }

    for (int tile = gbid; tile < nTiles; tile += 1024) {
        const int nbase = tile * 64;
        int gn = nbase + wave * 16 + row16;
        if (gn >= N) gn = N - 1;
        const float* __restrict__ xp = X + (size_t)gn * K + quad * 8;

        float4 xv[K / 16];
#pragma unroll
        for (int c = 0; c < K / 32; ++c) {
            xv[2 * c]     = *(const float4*)(xp + c * 32);
            xv[2 * c + 1] = *(const float4*)(xp + c * 32 + 4);
        }

        f32x4 acc[4] = {{0.f, 0.f, 0.f, 0.f}, {0.f, 0.f, 0.f, 0.f},
                        {0.f, 0.f, 0.f, 0.f}, {0.f, 0.f, 0.f, 0.f}};
#pragma unroll
        for (int kc = 0; kc < K; kc += 32) {
            float xs[8];
            *(float4*)&xs[0] = xv[kc / 16];
            *(float4*)&xs[4] = xv[kc / 16 + 1];
            bf16x8 ahi, alo;
#pragma unroll
            for (int j = 0; j < 8; ++j) {
                __bf16 hi = (__bf16)xs[j];
                ahi[j] = hi;
                alo[j] = (__bf16)(xs[j] - (float)hi);
            }
#pragma unroll
            for (int t = 0; t < 4; ++t) {
                bf16x8 bhi = *(const bf16x8*)&Whi[t * 16 + row16][kc + quad * 8];
                bf16x8 blo = *(const bf16x8*)&Wlo[t * 16 + row16][kc + quad * 8];
                acc[t] = __builtin_amdgcn_mfma_f32_16x16x32_bf16(ahi, bhi, acc[t], 0, 0, 0);
                acc[t] = __builtin_amdgcn_mfma_f32_16x16x32_bf16(ahi, blo, acc[t], 0, 0, 0);
                acc[t] = __builtin_amdgcn_mfma_f32_16x16x32_bf16(alo, bhi, acc[t], 0, 0, 0);
            }
        }

        float ps[4] = {0.f, 0.f, 0.f, 0.f};
        float pd[4] = {0.f, 0.f, 0.f, 0.f};
#pragma unroll
        for (int t = 0; t < 4; ++t) {
#pragma unroll
            for (int r = 0; r < 4; ++r) {
                int gm = nbase + wave * 16 + quad * 4 + r;
                if (gm < N) Hout[(size_t)gm * 64 + t * 16 + row16] = (__bf16)acc[t][r];
                ps[r] = fmaf(acc[t][r], asv[t], ps[r]);
                pd[r] = fmaf(acc[t][r], adv[t], pd[r]);
            }
        }
#pragma unroll
        for (int r = 0; r < 4; ++r) {
#pragma unroll
            for (int d = 1; d < 16; d <<= 1) {
                ps[r] += __shfl_xor(ps[r], d, 64);
                pd[r] += __shfl_xor(pd[r], d, 64);
            }
        }
        if (row16 == 0) {
#pragma unroll
            for (int r = 0; r < 4; ++r) {
                int gm = nbase + wave * 16 + quad * 4 + r;
                if (gm < N) { as_[gm] = ps[r]; ad_[gm] = pd[r]; }
            }
        }
    }
}

// ---------------- per-bucket CSR (rank-capture, atomic-free writes) --------

__global__ __launch_bounds__(512) void bucket_csr(const unsigned* __restrict__ ebuf,
                                                  const int* __restrict__ bucketCount,
                                                  int* __restrict__ offs,
                                                  int* __restrict__ csr, int N, int E) {
    __shared__ int hist[512], excls[512], wsum[8];
    const int b = blockIdx.x;
    const int t = threadIdx.x;
    const int lane = t & 63;
    const int w = t >> 6;

    // gbase = sum of bucketCount[0..b-1] via reduction
    int v = (t < 256 && t < b) ? bucketCount[t] : 0;
#pragma unroll
    for (int d = 32; d; d >>= 1) v += __shfl_xor(v, d, 64);
    if (lane == 0) wsum[w] = v;
    hist[t] = 0;
    __syncthreads();
    int gbase = 0;
#pragma unroll
    for (int i = 0; i < 8; ++i) gbase += wsum[i];
    const int cnt = bucketCount[b];
    if (b == 0 && t == 0) offs[N] = E;

    const unsigned* __restrict__ eb = ebuf + (size_t)b * BCAP;
    int rr[BCAP / 512];
#pragma unroll
    for (int i = 0; i < BCAP / 512; ++i) {
        int idx = i * 512 + t;
        if (idx < cnt) rr[i] = atomicAdd(&hist[eb[idx] & (BSIZE - 1)], 1);
    }
    __syncthreads();

    // 512-entry exclusive scan: wave scans + cross-wave combine
    int hv = hist[t];
    int incl = wave_incl_scan(hv, lane);
    if (lane == 63) wsum[w] = incl;
    __syncthreads();
    int prefix = 0;
    for (int i = 0; i < 8; ++i) prefix += (i < w) ? wsum[i] : 0;
    int excl = incl - hv + prefix;
    int n = b * BSIZE + t;
    if (n < N) offs[n] = gbase + excl;
    excls[t] = excl;
    __syncthreads();

#pragma unroll
    for (int i = 0; i < BCAP / 512; ++i) {
        int idx = i * 512 + t;
        if (idx < cnt) {
            unsigned rec = eb[idx];
            csr[gbase + excls[rec & (BSIZE - 1)] + rr[i]] = (int)(rec >> BSHIFT);
        }
    }
}

// ---------------- MFMA GEMM layer-2 (K=64, bf16 A, 2-term) ----------------

__global__ __launch_bounds__(256) void gemm_mfma2(const __bf16* __restrict__ X,
                                                  const float* __restrict__ W,
                                                  const float* __restrict__ a_src,
                                                  const float* __restrict__ a_dst,
                                                  __bf16* __restrict__ Hout,
                                                  float* __restrict__ as_,
                                                  float* __restrict__ ad_,
                                                  int N, int nTiles) {
    constexpr int K = 64;
    __shared__ __bf16 Whi[64][K + 8];
    __shared__ __bf16 Wlo[64][K + 8];
    for (int idx = threadIdx.x; idx < K * 64; idx += 256) {
        int k = idx >> 6, n = idx & 63;
        float w = W[idx];
        __bf16 hi = (__bf16)w;
        Whi[n][k] = hi;
        Wlo[n][k] = (__bf16)(w - (float)hi);
    }
    __syncthreads();

    const int lane  = threadIdx.x & 63;
    const int wave  = threadIdx.x >> 6;
    const int row16 = lane & 15;
    const int quad  = lane >> 4;

    float asv[4], adv[4];
#pragma unroll
    for (int t = 0; t < 4; ++t) {
        asv[t] = a_src[t * 16 + row16];
        adv[t] = a_dst[t * 16 + row16];
    }

    for (int tile = blockIdx.x; tile < nTiles; tile += gridDim.x) {
        const int nbase = tile * 64;
        int gn = nbase + wave * 16 + row16;
        if (gn >= N) gn = N - 1;
        const __bf16* __restrict__ xp = X + (size_t)gn * K + quad * 8;
        bf16x8 a0 = *(const bf16x8*)(xp);
        bf16x8 a1 = *(const bf16x8*)(xp + 32);

        f32x4 acc[4] = {{0.f, 0.f, 0.f, 0.f}, {0.f, 0.f, 0.f, 0.f},
                        {0.f, 0.f, 0.f, 0.f}, {0.f, 0.f, 0.f, 0.f}};
#pragma unroll
        for (int kc = 0; kc < K; kc += 32) {
            bf16x8 a = (kc == 0) ? a0 : a1;
#pragma unroll
            for (int t = 0; t < 4; ++t) {
                bf16x8 bhi = *(const bf16x8*)&Whi[t * 16 + row16][kc + quad * 8];
                bf16x8 blo = *(const bf16x8*)&Wlo[t * 16 + row16][kc + quad * 8];
                acc[t] = __builtin_amdgcn_mfma_f32_16x16x32_bf16(a, bhi, acc[t], 0, 0, 0);
                acc[t] = __builtin_amdgcn_mfma_f32_16x16x32_bf16(a, blo, acc[t], 0, 0, 0);
            }
        }

        float ps[4] = {0.f, 0.f, 0.f, 0.f};
        float pd[4] = {0.f, 0.f, 0.f, 0.f};
#pragma unroll
        for (int t = 0; t < 4; ++t) {
#pragma unroll
            for (int r = 0; r < 4; ++r) {
                int gm = nbase + wave * 16 + quad * 4 + r;
                if (gm < N) Hout[(size_t)gm * 64 + t * 16 + row16] = (__bf16)acc[t][r];
                ps[r] = fmaf(acc[t][r], asv[t], ps[r]);
                pd[r] = fmaf(acc[t][r], adv[t], pd[r]);
            }
        }
#pragma unroll
        for (int r = 0; r < 4; ++r) {
#pragma unroll
            for (int d = 1; d < 16; d <<= 1) {
                ps[r] += __shfl_xor(ps[r], d, 64);
                pd[r] += __shfl_xor(pd[r], d, 64);
            }
        }
        if (row16 == 0) {
#pragma unroll
            for (int r = 0; r < 4; ++r) {
                int gm = nbase + wave * 16 + quad * 4 + r;
                if (gm < N) { as_[gm] = ps[r]; ad_[gm] = pd[r]; }
            }
        }
    }
}

// ---------------- fused segment softmax + aggregation (4x16, bf16x4) -------

__global__ __launch_bounds__(256) void gat_agg(const __bf16* __restrict__ h,
                                               const float* __restrict__ as_,
                                               const float* __restrict__ ad_,
                                               const float* __restrict__ bias,
                                               const int* __restrict__ offs,
                                               const int* __restrict__ csr,
                                               __bf16* __restrict__ out,
                                               int N, int do_relu) {
    int gtid = blockIdx.x * blockDim.x + threadIdx.x;
    int n = __builtin_amdgcn_readfirstlane(gtid >> 6);
    if (n >= N) return;
    const int lane = threadIdx.x & 63;
    const int g  = lane >> 4;   // edge group 0..3
    const int fl = lane & 15;   // feature quad index

    int beg = offs[n], end = offs[n + 1];
    float adn = ad_[n];
    float p_self = __expf(lrelu(as_[n] + adn));

    float den = p_self;
    float ax, ay, az, aw;
    {
        bf16x4 t = *(const bf16x4*)(h + (size_t)n * 64 + fl * 4);
        float m0 = (g == 0) ? p_self : 0.f;
        ax = m0 * (float)t[0];
        ay = m0 * (float)t[1];
        az = m0 * (float)t[2];
        aw = m0 * (float)t[3];
    }

    for (int c0 = beg; c0 < end; c0 += 64) {
        int cnt = end - c0;
        if (cnt > 64) cnt = 64;
        int   s_l = (lane < cnt) ? csr[c0 + lane] : 0;
        float p_l = (lane < cnt) ? __expf(lrelu(as_[s_l] + adn)) : 0.f;
        float csum = p_l;
#pragma unroll
        for (int d = 32; d; d >>= 1) csum += __shfl_xor(csum, d, 64);
        den += csum;

        int rounds = (cnt + 3) >> 2;
        for (int r = 0; r < rounds; r += 4) {
            int j0 = (r + 0) * 4 + g, j1 = (r + 1) * 4 + g;
            int j2 = (r + 2) * 4 + g, j3 = (r + 3) * 4 + g;
            float w0 = __shfl(p_l, j0, 64), w1 = __shfl(p_l, j1, 64);
            float w2 = __shfl(p_l, j2, 64), w3 = __shfl(p_l, j3, 64);
            int s0 = __shfl(s_l, j0, 64), s1 = __shfl(s_l, j1, 64);
            int s2 = __shfl(s_l, j2, 64), s3 = __shfl(s_l, j3, 64);
            bf16x4 h0 = *(const bf16x4*)(h + (size_t)s0 * 64 + fl * 4);
            bf16x4 h1 = *(const bf16x4*)(h + (size_t)s1 * 64 + fl * 4);
            bf16x4 h2 = *(const bf16x4*)(h + (size_t)s2 * 64 + fl * 4);
            bf16x4 h3 = *(const bf16x4*)(h + (size_t)s3 * 64 + fl * 4);
            ax = fmaf(w0, (float)h0[0], ax); ay = fmaf(w0, (float)h0[1], ay);
            az = fmaf(w0, (float)h0[2], az); aw = fmaf(w0, (float)h0[3], aw);
            ax = fmaf(w1, (float)h1[0], ax); ay = fmaf(w1, (float)h1[1], ay);
            az = fmaf(w1, (float)h1[2], az); aw = fmaf(w1, (float)h1[3], aw);
            ax = fmaf(w2, (float)h2[0], ax); ay = fmaf(w2, (float)h2[1], ay);
            az = fmaf(w2, (float)h2[2], az); aw = fmaf(w2, (float)h2[3], aw);
            ax = fmaf(w3, (float)h3[0], ax); ay = fmaf(w3, (float)h3[1], ay);
            az = fmaf(w3, (float)h3[2], az); aw = fmaf(w3, (float)h3[3], aw);
        }
    }

#pragma unroll
    for (int d = 16; d <= 32; d <<= 1) {
        ax += __shfl_xor(ax, d, 64);
        ay += __shfl_xor(ay, d, 64);
        az += __shfl_xor(az, d, 64);
        aw += __shfl_xor(aw, d, 64);
    }
    if (g == 0) {
        float inv = 1.f / (den + 1e-16f);
        const float4 b4 = *(const float4*)(bias + fl * 4);
        bf16x4 ov;
        float o0 = fmaf(ax, inv, b4.x);
        float o1 = fmaf(ay, inv, b4.y);
        float o2 = fmaf(az, inv, b4.z);
        float o3 = fmaf(aw, inv, b4.w);
        if (do_relu) {
            o0 = fmaxf(o0, 0.f); o1 = fmaxf(o1, 0.f);
            o2 = fmaxf(o2, 0.f); o3 = fmaxf(o3, 0.f);
        }
        ov[0] = (__bf16)o0; ov[1] = (__bf16)o1;
        ov[2] = (__bf16)o2; ov[3] = (__bf16)o3;
        *(bf16x4*)(out + (size_t)n * 64 + fl * 4) = ov;
    }
}

// ---------------- final linear (bf16 A, 2-term) + log_softmax --------------

__global__ __launch_bounds__(256) void final_lsm(const __bf16* __restrict__ h,
                                                 const float* __restrict__ Wl,
                                                 const float* __restrict__ bl,
                                                 float* __restrict__ out,
                                                 int N, int nTiles) {
    __shared__ __bf16 Whi[48][72];
    __shared__ __bf16 Wlo[48][72];
    __shared__ float bls[48];
    for (int idx = threadIdx.x; idx < 48 * 64; idx += 256) {
        int c = idx >> 6, k = idx & 63;
        float w = (c < 40) ? Wl[k * 40 + c] : 0.f;
        __bf16 hi = (__bf16)w;
        Whi[c][k] = hi;
        Wlo[c][k] = (__bf16)(w - (float)hi);
    }
    if (threadIdx.x < 48) bls[threadIdx.x] = (threadIdx.x < 40) ? bl[threadIdx.x] : 0.f;
    __syncthreads();

    const int lane  = threadIdx.x & 63;
    const int wave  = threadIdx.x >> 6;
    const int col16 = lane & 15;
    const int quad  = lane >> 4;

    for (int tile = blockIdx.x; tile < nTiles; tile += gridDim.x) {
        const int nbase = tile * 64;
        int gn = nbase + wave * 16 + col16;
        if (gn >= N) gn = N - 1;
        const __bf16* __restrict__ xp = h + (size_t)gn * 64 + quad * 8;
        bf16x8 a0 = *(const bf16x8*)(xp);
        bf16x8 a1 = *(const bf16x8*)(xp + 32);

        f32x4 acc[3] = {{0.f, 0.f, 0.f, 0.f}, {0.f, 0.f, 0.f, 0.f},
                        {0.f, 0.f, 0.f, 0.f}};
#pragma unroll
        for (int kc = 0; kc < 64; kc += 32) {
            bf16x8 a = (kc == 0) ? a0 : a1;
#pragma unroll
            for (int t = 0; t < 3; ++t) {
                bf16x8 bhi = *(const bf16x8*)&Whi[t * 16 + col16][kc + quad * 8];
                bf16x8 blo = *(const bf16x8*)&Wlo[t * 16 + col16][kc + quad * 8];
                acc[t] = __builtin_amdgcn_mfma_f32_16x16x32_bf16(a, bhi, acc[t], 0, 0, 0);
                acc[t] = __builtin_amdgcn_mfma_f32_16x16x32_bf16(a, blo, acc[t], 0, 0, 0);
            }
        }

#pragma unroll
        for (int r = 0; r < 4; ++r) {
            int gm = nbase + wave * 16 + quad * 4 + r;
            float l0 = acc[0][r] + bls[col16];
            float l1 = acc[1][r] + bls[16 + col16];
            float l2 = (col16 < 8) ? (acc[2][r] + bls[32 + col16]) : NEG_BIG;
            float mx = fmaxf(fmaxf(l0, l1), l2);
#pragma unroll
            for (int d = 1; d < 16; d <<= 1) mx = fmaxf(mx, __shfl_xor(mx, d, 64));
            float s = __expf(l0 - mx) + __expf(l1 - mx) +
                      ((col16 < 8) ? __expf(l2 - mx) : 0.f);
#pragma unroll
            for (int d = 1; d < 16; d <<= 1) s += __shfl_xor(s, d, 64);
            float lse = mx + __logf(s);
            if (gm < N) {
                out[(size_t)gm * 40 + col16]      = l0 - lse;
                out[(size_t)gm * 40 + 16 + col16] = l1 - lse;
                if (col16 < 8) out[(size_t)gm * 40 + 32 + col16] = l2 - lse;
            }
        }
    }
}

// ---------------- launch ----------------

extern "C" void kernel_launch(void* const* d_in, const int* in_sizes, int n_in,
                              void* d_out, int out_size, void* d_ws, size_t ws_size,
                              hipStream_t stream) {
    const float* x      = (const float*)d_in[0];
    const int*   ei     = (const int*)d_in[1];
    const float* W1     = (const float*)d_in[2];
    const float* a_src1 = (const float*)d_in[3];
    const float* a_dst1 = (const float*)d_in[4];
    const float* b1     = (const float*)d_in[5];
    const float* W2     = (const float*)d_in[6];
    const float* a_src2 = (const float*)d_in[7];
    const float* a_dst2 = (const float*)d_in[8];
    const float* b2     = (const float*)d_in[9];
    const float* Wl     = (const float*)d_in[10];
    const float* bl     = (const float*)d_in[11];

    const int N = in_sizes[0] / 128;
    const int E = in_sizes[1] / 2;
    const int* src = ei;
    const int* dst = ei + E;
    const int nbuck = (N + BSIZE - 1) >> BSHIFT;
    const int SB = (E + EPB - 1) / EPB;

    char* p = (char*)d_ws;
    auto alloc = [&](size_t bytes) -> void* {
        void* r = (void*)p;
        p += (bytes + 255) & ~(size_t)255;
        return r;
    };
    int*      offs        = (int*)alloc((size_t)(N + 1) * 4);
    int*      bucketCount = (int*)alloc(256 * 4);
    unsigned* ebuf        = (unsigned*)alloc((size_t)nbuck * BCAP * 4);
    int*      csr         = (int*)alloc((size_t)E * 4);
    __bf16*   hbf         = (__bf16*)alloc((size_t)N * 64 * 2);  // gemm h out
    __bf16*   habg        = (__bf16*)alloc((size_t)N * 64 * 2);  // agg out
    float*    as_         = (float*)alloc((size_t)N * 4);
    float*    ad_         = (float*)alloc((size_t)N * 4);

    hipMemsetAsync(bucketCount, 0, 256 * 4, stream);

    const int nTiles = (N + 63) / 64;
    int aggBlocks = (N * 64 + 255) / 256;

    fused_scatter_gemm<<<SB + 1024, 256, 0, stream>>>(
        src, dst, bucketCount, ebuf, E, SB,
        x, W1, a_src1, a_dst1, hbf, as_, ad_, N, nTiles);
    bucket_csr<<<nbuck, 512, 0, stream>>>(ebuf, bucketCount, offs, csr, N, E);
    gat_agg<<<aggBlocks, 256, 0, stream>>>(hbf, as_, ad_, b1, offs, csr, habg, N, 1);
    gemm_mfma2<<<1024, 256, 0, stream>>>(habg, W2, a_src2, a_dst2, hbf, as_, ad_, N, nTiles);
    gat_agg<<<aggBlocks, 256, 0, stream>>>(hbf, as_, ad_, b2, offs, csr, habg, N, 0);
    final_lsm<<<nTiles, 256, 0, stream>>>(habg, Wl, bl, (float*)d_out, N, nTiles);
}